// Round 1
// baseline (1040.462 us; speedup 1.0000x reference)
//
#include <hip/hip_runtime.h>
#include <math.h>

// Problem constants
#define TSEQ  2048
#define BATCH 2
#define NH    16
#define HD    64
#define CDIM  1024
#define N3C   3072
#define EPSY  1e-6f

// ---------------------------------------------------------------------------
// Column sums of squares for w_attn (1024x3072) and w_proj (1024x1024).
// ks[0..3071] = w_attn col norms^2 ; ks[3072..4095] = w_proj col norms^2
// grid 64 blocks x 256 thr: 64 cols/block, 4-way K split, LDS reduce.
__global__ void colsq_kernel(const float* __restrict__ wa,
                             const float* __restrict__ wp,
                             float* __restrict__ ks) {
    int bid = blockIdx.x, tid = threadIdx.x;
    int c = tid & 63, kq = tid >> 6;
    const float* W; int N, col, outoff;
    if (bid < 48) { W = wa; N = N3C;  col = bid * 64 + c;        outoff = 0;    }
    else          { W = wp; N = CDIM; col = (bid - 48) * 64 + c; outoff = N3C; }
    float s = 0.f;
    int i0 = kq * 256;
    #pragma unroll 4
    for (int i = i0; i < i0 + 256; ++i) {
        float v = W[(size_t)i * N + col];
        s = fmaf(v, v, s);
    }
    __shared__ float red[256];
    red[tid] = s;
    __syncthreads();
    if (kq == 0) ks[outoff + col] = red[c] + red[64 + c] + red[128 + c] + red[192 + c];
}

// ---------------------------------------------------------------------------
// Row sums of squares: out[row] = sum_k X[row*K+k]^2.  grid = rows, block 256.
__global__ void rowsq_kernel(const float* __restrict__ X, float* __restrict__ out, int K) {
    int row = blockIdx.x, tid = threadIdx.x;
    const float* p = X + (size_t)row * K;
    float s = 0.f;
    for (int i = tid; i < K; i += 256) { float v = p[i]; s = fmaf(v, v, s); }
    #pragma unroll
    for (int off = 32; off; off >>= 1) s += __shfl_down(s, off, 64);
    __shared__ float red[4];
    if ((tid & 63) == 0) red[tid >> 6] = s;
    __syncthreads();
    if (tid == 0) out[row] = red[0] + red[1] + red[2] + red[3];
}

// ---------------------------------------------------------------------------
// fp32 GEMM (M x K) @ (K x N) with fused yat epilogue:
//   y = dot^2 / (rowsq + colsq - 2 dot + eps) * scale + bias
// 128x128 tile, 256 threads, 8x8 acc per thread (split 4+4 rows/cols),
// LDS stride 132 (pad) -> conflict-free b128 fragment reads.
#define KT   32
#define LDSP 132
__global__ __launch_bounds__(256)
void gemm_yat(const float* __restrict__ A, const float* __restrict__ Bw,
              const float* __restrict__ bias, const float* __restrict__ rowsq,
              const float* __restrict__ colsq, const float* __restrict__ alphap,
              float* __restrict__ outp, int M, int N, int K, float outf) {
    __shared__ float As[KT * LDSP];
    __shared__ float Bs[KT * LDSP];
    int tid = threadIdx.x;
    int tx = tid & 15, ty = tid >> 4;
    int bm = blockIdx.y * 128;
    int bn = blockIdx.x * 128;

    float acc[8][8];
    #pragma unroll
    for (int i = 0; i < 8; ++i)
        #pragma unroll
        for (int j = 0; j < 8; ++j) acc[i][j] = 0.f;

    int r0 = ty << 2, c0 = tx << 2;

    for (int kt = 0; kt < K; kt += KT) {
        // A tile 128x32 -> As[k][row] (transposed store)
        #pragma unroll
        for (int jj = 0; jj < 4; ++jj) {
            int f = tid + 256 * jj;
            int row = f >> 3;
            int k4 = (f & 7) << 2;
            float4 v = *(const float4*)(A + (size_t)(bm + row) * K + kt + k4);
            As[(k4 + 0) * LDSP + row] = v.x;
            As[(k4 + 1) * LDSP + row] = v.y;
            As[(k4 + 2) * LDSP + row] = v.z;
            As[(k4 + 3) * LDSP + row] = v.w;
        }
        // B tile 32x128 -> Bs[k][col] (direct f4 store)
        #pragma unroll
        for (int jj = 0; jj < 4; ++jj) {
            int f = tid + 256 * jj;
            int krow = f >> 5;
            int c4 = (f & 31) << 2;
            float4 v = *(const float4*)(Bw + (size_t)(kt + krow) * N + bn + c4);
            *(float4*)(Bs + krow * LDSP + c4) = v;
        }
        __syncthreads();
        #pragma unroll 8
        for (int k = 0; k < KT; ++k) {
            float4 a0 = *(const float4*)(As + k * LDSP + r0);
            float4 a1 = *(const float4*)(As + k * LDSP + 64 + r0);
            float4 b0 = *(const float4*)(Bs + k * LDSP + c0);
            float4 b1 = *(const float4*)(Bs + k * LDSP + 64 + c0);
            float av[8] = {a0.x, a0.y, a0.z, a0.w, a1.x, a1.y, a1.z, a1.w};
            float bv[8] = {b0.x, b0.y, b0.z, b0.w, b1.x, b1.y, b1.z, b1.w};
            #pragma unroll
            for (int i = 0; i < 8; ++i)
                #pragma unroll
                for (int j = 0; j < 8; ++j)
                    acc[i][j] = fmaf(av[i], bv[j], acc[i][j]);
        }
        __syncthreads();
    }

    float alpha = alphap[0];
    float scale = powf(sqrtf(outf) / logf(1.0f + outf), alpha);
    #pragma unroll
    for (int ii = 0; ii < 8; ++ii) {
        int r = bm + ((ii < 4) ? (r0 + ii) : (64 + r0 + ii - 4));
        float rs = rowsq[r];
        #pragma unroll
        for (int g = 0; g < 2; ++g) {
            int cb = bn + (g ? (64 + c0) : c0);
            float4 ov;
            float* op = &ov.x;
            #pragma unroll
            for (int jj = 0; jj < 4; ++jj) {
                float dot = acc[ii][g * 4 + jj];
                int c = cb + jj;
                float dist = rs + colsq[c] - 2.0f * dot + EPSY;
                op[jj] = dot * dot / dist * scale + bias[c];
            }
            *(float4*)(outp + (size_t)r * N + cb) = ov;
        }
    }
}

// ---------------------------------------------------------------------------
// In-place rotary on q,k halves of qkv [B*T, 3*C].
// One thread per (b,t,which,h,j) pair, j in [0,32): mixes d=j and d=j+32.
__global__ void rotary_kernel(float* __restrict__ qkv) {
    int idx = blockIdx.x * 256 + threadIdx.x;  // 2^22 total
    int j     = idx & 31;
    int h     = (idx >> 5) & 15;
    int which = (idx >> 9) & 1;
    int t     = (idx >> 10) & 2047;
    int b     = idx >> 21;
    size_t base = ((size_t)(b * TSEQ + t)) * N3C + which * CDIM + h * HD + j;
    float x1 = qkv[base], x2 = qkv[base + 32];
    float inv = powf(10000.0f, -(float)(2 * j) / 64.0f);
    float ang = (float)t * inv;
    float sn = sinf(ang), cs = cosf(ang);
    qkv[base]      = x1 * cs - x2 * sn;
    qkv[base + 32] = x2 * cs + x1 * sn;
}

// ---------------------------------------------------------------------------
// Causal flash attention, fp32. Tiles 64x64, block 256 (4x4 micro-tile/thr).
// grid (16, B*H): each block does query tiles qb0 and 31-qb0 -> balanced
// causal work (33 K-tiles per block).
#define DP 68
__global__ __launch_bounds__(256)
void attn_kernel(const float* __restrict__ qkv, float* __restrict__ ctx) {
    int bh = blockIdx.y;
    int b = bh >> 4, h = bh & 15;
    int qb0 = blockIdx.x;
    int tid = threadIdx.x;
    int tx = tid & 15, ty = tid >> 4;

    __shared__ float Qs[64 * DP];   // [d][r], pre-scaled by 1/8
    __shared__ float KPs[64 * DP];  // K as [d][c] during S; P as [c][r] during PV
    __shared__ float Vs[64 * DP];   // [c][d]

    for (int pass = 0; pass < 2; ++pass) {
        int qb = pass ? (31 - qb0) : qb0;
        __syncthreads();  // protect Qs overwrite across passes
        #pragma unroll
        for (int jj = 0; jj < 4; ++jj) {
            int f = tid + 256 * jj;
            int r = f >> 4;
            int d4 = (f & 15) << 2;
            const float* src = qkv + ((size_t)((b << 11) + (qb << 6) + r)) * N3C + (h << 6) + d4;
            float4 v = *(const float4*)src;
            Qs[(d4 + 0) * DP + r] = v.x * 0.125f;
            Qs[(d4 + 1) * DP + r] = v.y * 0.125f;
            Qs[(d4 + 2) * DP + r] = v.z * 0.125f;
            Qs[(d4 + 3) * DP + r] = v.w * 0.125f;
        }

        float o[4][4];
        float m[4], l[4];
        #pragma unroll
        for (int i = 0; i < 4; ++i) {
            m[i] = -1e30f; l[i] = 0.f;
            #pragma unroll
            for (int j = 0; j < 4; ++j) o[i][j] = 0.f;
        }

        for (int kt = 0; kt <= qb; ++kt) {
            // load K (transposed) and V tiles
            #pragma unroll
            for (int jj = 0; jj < 4; ++jj) {
                int f = tid + 256 * jj;
                int c = f >> 4;
                int d4 = (f & 15) << 2;
                size_t rowbase = ((size_t)((b << 11) + (kt << 6) + c)) * N3C + (h << 6) + d4;
                float4 kv = *(const float4*)(qkv + rowbase + CDIM);
                KPs[(d4 + 0) * DP + c] = kv.x;
                KPs[(d4 + 1) * DP + c] = kv.y;
                KPs[(d4 + 2) * DP + c] = kv.z;
                KPs[(d4 + 3) * DP + c] = kv.w;
                float4 vv = *(const float4*)(qkv + rowbase + 2 * CDIM);
                *(float4*)(Vs + c * DP + d4) = vv;
            }
            __syncthreads();

            float s[4][4];
            #pragma unroll
            for (int i = 0; i < 4; ++i)
                #pragma unroll
                for (int j = 0; j < 4; ++j) s[i][j] = 0.f;
            #pragma unroll 8
            for (int d = 0; d < 64; ++d) {
                float4 a  = *(const float4*)(Qs  + d * DP + (ty << 2));
                float4 kb = *(const float4*)(KPs + d * DP + (tx << 2));
                float av[4] = {a.x, a.y, a.z, a.w};
                float bv[4] = {kb.x, kb.y, kb.z, kb.w};
                #pragma unroll
                for (int i = 0; i < 4; ++i)
                    #pragma unroll
                    for (int j = 0; j < 4; ++j)
                        s[i][j] = fmaf(av[i], bv[j], s[i][j]);
            }
            if (kt == qb) {
                #pragma unroll
                for (int i = 0; i < 4; ++i) {
                    int qr = (ty << 2) + i;
                    #pragma unroll
                    for (int j = 0; j < 4; ++j) {
                        int kc = (tx << 2) + j;
                        if (kc > qr) s[i][j] = -1e30f;
                    }
                }
            }
            // online softmax
            #pragma unroll
            for (int i = 0; i < 4; ++i) {
                float mt = fmaxf(fmaxf(s[i][0], s[i][1]), fmaxf(s[i][2], s[i][3]));
                #pragma unroll
                for (int off = 1; off < 16; off <<= 1) mt = fmaxf(mt, __shfl_xor(mt, off, 64));
                float mn = fmaxf(m[i], mt);
                float al = expf(m[i] - mn);
                float ps = 0.f;
                #pragma unroll
                for (int j = 0; j < 4; ++j) { s[i][j] = expf(s[i][j] - mn); ps += s[i][j]; }
                #pragma unroll
                for (int off = 1; off < 16; off <<= 1) ps += __shfl_xor(ps, off, 64);
                l[i] = l[i] * al + ps;
                m[i] = mn;
                #pragma unroll
                for (int j = 0; j < 4; ++j) o[i][j] *= al;
            }
            __syncthreads();  // all S-phase reads of KPs done
            #pragma unroll
            for (int i = 0; i < 4; ++i)
                #pragma unroll
                for (int j = 0; j < 4; ++j)
                    KPs[((tx << 2) + j) * DP + (ty << 2) + i] = s[i][j];
            __syncthreads();
            // PV
            #pragma unroll 8
            for (int c = 0; c < 64; ++c) {
                float4 a  = *(const float4*)(KPs + c * DP + (ty << 2));
                float4 vb = *(const float4*)(Vs  + c * DP + (tx << 2));
                float av[4] = {a.x, a.y, a.z, a.w};
                float bv[4] = {vb.x, vb.y, vb.z, vb.w};
                #pragma unroll
                for (int i = 0; i < 4; ++i)
                    #pragma unroll
                    for (int j = 0; j < 4; ++j)
                        o[i][j] = fmaf(av[i], bv[j], o[i][j]);
            }
            __syncthreads();  // before next tile's K/V overwrite
        }

        #pragma unroll
        for (int i = 0; i < 4; ++i) {
            float inv = 1.f / l[i];
            float4 r;
            r.x = o[i][0] * inv; r.y = o[i][1] * inv;
            r.z = o[i][2] * inv; r.w = o[i][3] * inv;
            *(float4*)(ctx + ((size_t)((b << 11) + (qb << 6) + (ty << 2) + i)) * CDIM
                       + (h << 6) + (tx << 2)) = r;
        }
    }
}

// ---------------------------------------------------------------------------
extern "C" void kernel_launch(void* const* d_in, const int* in_sizes, int n_in,
                              void* d_out, int out_size, void* d_ws, size_t ws_size,
                              hipStream_t stream) {
    const float* x      = (const float*)d_in[0];
    // d_in[1] = mask (causal tril) -- structure known, not read
    const float* w_attn = (const float*)d_in[2];
    const float* b_attn = (const float*)d_in[3];
    const float* a_attn = (const float*)d_in[4];
    const float* w_proj = (const float*)d_in[5];
    const float* b_proj = (const float*)d_in[6];
    const float* a_proj = (const float*)d_in[7];
    float* outp = (float*)d_out;

    float* ws  = (float*)d_ws;
    float* ksq = ws;                 // 4096: [0,3072) attn, [3072,4096) proj
    float* xsq = ws + 4096;          // 4096
    float* osq = ws + 8192;          // 4096
    float* qkv = ws + 16384;         // B*T*3C = 12582912
    float* ctx = ws + 16384 + (size_t)BATCH * TSEQ * N3C;  // B*T*C = 4194304

    colsq_kernel<<<64, 256, 0, stream>>>(w_attn, w_proj, ksq);
    rowsq_kernel<<<BATCH * TSEQ, 256, 0, stream>>>(x, xsq, CDIM);
    gemm_yat<<<dim3(N3C / 128, (BATCH * TSEQ) / 128), 256, 0, stream>>>(
        x, w_attn, b_attn, xsq, ksq, a_attn, qkv,
        BATCH * TSEQ, N3C, CDIM, (float)N3C);
    rotary_kernel<<<(BATCH * TSEQ * 2 * NH * 32) / 256, 256, 0, stream>>>(qkv);
    attn_kernel<<<dim3(16, BATCH * NH), 256, 0, stream>>>(qkv, ctx);
    rowsq_kernel<<<BATCH * TSEQ, 256, 0, stream>>>(ctx, osq, CDIM);
    gemm_yat<<<dim3(CDIM / 128, (BATCH * TSEQ) / 128), 256, 0, stream>>>(
        ctx, w_proj, b_proj, osq, ksq + N3C, a_proj, outp,
        BATCH * TSEQ, CDIM, CDIM, (float)CDIM);
}

// Round 2
// 427.831 us; speedup vs baseline: 2.4319x; 2.4319x over previous
//
#include <hip/hip_runtime.h>
#include <math.h>

#define TSEQ  2048
#define BATCH 2
#define NH    16
#define HD    64
#define CDIM  1024
#define N3C   3072
#define EPSY  1e-6f

typedef unsigned short u16;
typedef __attribute__((ext_vector_type(8))) short bf16x8;   // 8 bf16 = 4 VGPRs
typedef __attribute__((ext_vector_type(4))) float f32x4;

#define MFMA16(a, b, c) __builtin_amdgcn_mfma_f32_16x16x32_bf16(a, b, c, 0, 0, 0)

__device__ __forceinline__ u16 f2bf(float f) {
    unsigned u = __float_as_uint(f);
    return (u16)((u + 0x7fffu + ((u >> 16) & 1u)) >> 16);
}
__device__ __forceinline__ float bf2f(u16 h) {
    return __uint_as_float(((unsigned)h) << 16);
}
__device__ __forceinline__ void gload16(const void* g, void* l) {
    __builtin_amdgcn_global_load_lds(
        (const __attribute__((address_space(1))) unsigned int*)g,
        (__attribute__((address_space(3))) unsigned int*)l, 16, 0, 0);
}

// ---------------------------------------------------------------------------
// Column sums of squares for w_attn (1024x3072) and w_proj (1024x1024), fp32.
__global__ void colsq_kernel(const float* __restrict__ wa,
                             const float* __restrict__ wp,
                             float* __restrict__ ks) {
    int bid = blockIdx.x, tid = threadIdx.x;
    int c = tid & 63, kq = tid >> 6;
    const float* W; int N, col, outoff;
    if (bid < 48) { W = wa; N = N3C;  col = bid * 64 + c;        outoff = 0;   }
    else          { W = wp; N = CDIM; col = (bid - 48) * 64 + c; outoff = N3C; }
    float s = 0.f;
    int i0 = kq * 256;
    #pragma unroll 4
    for (int i = i0; i < i0 + 256; ++i) {
        float v = W[(size_t)i * N + col];
        s = fmaf(v, v, s);
    }
    __shared__ float red[256];
    red[tid] = s;
    __syncthreads();
    if (kq == 0) ks[outoff + col] = red[c] + red[64 + c] + red[128 + c] + red[192 + c];
}

// ---------------------------------------------------------------------------
// Row-wise: fp32 [rows x 1024] -> bf16 hi/lo [rows x 1024] + rowsq fp32.
__global__ void convert_rows(const float* __restrict__ X, u16* __restrict__ Xhi,
                             u16* __restrict__ Xlo, float* __restrict__ rsq) {
    int row = blockIdx.x, tid = threadIdx.x;
    int lane = tid & 63, wv = tid >> 6;
    size_t base = (size_t)row * CDIM + tid * 4;
    float4 v = *(const float4*)(X + base);
    ushort4 hi, lo;
    hi.x = f2bf(v.x); lo.x = f2bf(v.x - bf2f(hi.x));
    hi.y = f2bf(v.y); lo.y = f2bf(v.y - bf2f(hi.y));
    hi.z = f2bf(v.z); lo.z = f2bf(v.z - bf2f(hi.z));
    hi.w = f2bf(v.w); lo.w = f2bf(v.w - bf2f(hi.w));
    *(ushort4*)(Xhi + base) = hi;
    *(ushort4*)(Xlo + base) = lo;
    float s = v.x * v.x + v.y * v.y + v.z * v.z + v.w * v.w;
    #pragma unroll
    for (int off = 32; off; off >>= 1) s += __shfl_down(s, off, 64);
    __shared__ float red[4];
    if (lane == 0) red[wv] = s;
    __syncthreads();
    if (tid == 0) rsq[row] = red[0] + red[1] + red[2] + red[3];
}

// ---------------------------------------------------------------------------
// W [K x N] fp32 -> Wt hi/lo [N x K] bf16 (transpose via LDS 64x64 tile).
__global__ void convert_wT(const float* __restrict__ W, u16* __restrict__ Whi,
                           u16* __restrict__ Wlo, int K, int N) {
    __shared__ float tile[64][68];
    int k0 = blockIdx.y * 64, n0 = blockIdx.x * 64;
    int tid = threadIdx.x;
    int r = tid >> 4, c4 = (tid & 15) * 4;
    #pragma unroll
    for (int i = 0; i < 4; ++i) {
        int k = k0 + r + i * 16;
        float4 v = *(const float4*)(W + (size_t)k * N + n0 + c4);
        *(float4*)&tile[r + i * 16][c4] = v;
    }
    __syncthreads();
    int n = tid >> 4, k4 = (tid & 15) * 4;
    #pragma unroll
    for (int i = 0; i < 4; ++i) {
        int nn = n + i * 16;
        float a = tile[k4 + 0][nn], b = tile[k4 + 1][nn];
        float c = tile[k4 + 2][nn], d = tile[k4 + 3][nn];
        ushort4 hi, lo;
        hi.x = f2bf(a); lo.x = f2bf(a - bf2f(hi.x));
        hi.y = f2bf(b); lo.y = f2bf(b - bf2f(hi.y));
        hi.z = f2bf(c); lo.z = f2bf(c - bf2f(hi.z));
        hi.w = f2bf(d); lo.w = f2bf(d - bf2f(hi.w));
        size_t o = (size_t)(n0 + nn) * K + k0 + k4;
        *(ushort4*)(Whi + o) = hi;
        *(ushort4*)(Wlo + o) = lo;
    }
}

// ---------------------------------------------------------------------------
// Split-bf16 MFMA GEMM with fused yat epilogue.
// A hi/lo [M x K], B hi/lo [N x K] (pre-transposed). dot = AhBh + AlBh + AhBl.
template<int BN, int WR, int WC>
__global__ __launch_bounds__(256) void gemm_yat_mfma(
    const u16* __restrict__ Ah, const u16* __restrict__ Al,
    const u16* __restrict__ Bh, const u16* __restrict__ Bl,
    const float* __restrict__ bias, const float* __restrict__ rowsq,
    const float* __restrict__ colsq, const float* __restrict__ alphap,
    float* __restrict__ outp, int M, int N, int K, float outf) {
    constexpr int BM = 128;
    constexpr int BK = 32;
    constexpr int MT = BM / WR / 16;
    constexpr int NT = BN / WC / 16;
    __shared__ u16 Ash[BM * BK], Asl[BM * BK], Bsh[BN * BK], Bsl[BN * BK];
    int tid = threadIdx.x;
    int lane = tid & 63, wv = tid >> 6;
    int quad = lane >> 4, l15 = lane & 15;
    int wr = wv / WC, wc = wv % WC;
    int bm = blockIdx.y * BM, bn = blockIdx.x * BN;
    int rsub = lane >> 2, csub = (lane & 3) * 8;

    f32x4 acc[MT][NT];
    #pragma unroll
    for (int i = 0; i < MT; ++i)
        #pragma unroll
        for (int j = 0; j < NT; ++j) acc[i][j] = (f32x4){0.f, 0.f, 0.f, 0.f};

    for (int kt = 0; kt < K; kt += BK) {
        #pragma unroll
        for (int i = 0; i < BM / 64; ++i) {
            int r = i * 64 + wv * 16 + rsub;
            size_t go = (size_t)(bm + r) * K + kt + csub;
            gload16(Ah + go, &Ash[r * BK + csub]);
            gload16(Al + go, &Asl[r * BK + csub]);
        }
        #pragma unroll
        for (int i = 0; i < BN / 64; ++i) {
            int r = i * 64 + wv * 16 + rsub;
            size_t go = (size_t)(bn + r) * K + kt + csub;
            gload16(Bh + go, &Bsh[r * BK + csub]);
            gload16(Bl + go, &Bsl[r * BK + csub]);
        }
        __syncthreads();
        bf16x8 fah[MT], fal[MT], fbh[NT], fbl[NT];
        #pragma unroll
        for (int i = 0; i < MT; ++i) {
            int r = wr * (BM / WR) + i * 16 + l15;
            fah[i] = *(const bf16x8*)&Ash[r * BK + quad * 8];
            fal[i] = *(const bf16x8*)&Asl[r * BK + quad * 8];
        }
        #pragma unroll
        for (int j = 0; j < NT; ++j) {
            int r = wc * (BN / WC) + j * 16 + l15;
            fbh[j] = *(const bf16x8*)&Bsh[r * BK + quad * 8];
            fbl[j] = *(const bf16x8*)&Bsl[r * BK + quad * 8];
        }
        #pragma unroll
        for (int i = 0; i < MT; ++i)
            #pragma unroll
            for (int j = 0; j < NT; ++j) {
                acc[i][j] = MFMA16(fah[i], fbh[j], acc[i][j]);
                acc[i][j] = MFMA16(fal[i], fbh[j], acc[i][j]);
                acc[i][j] = MFMA16(fah[i], fbl[j], acc[i][j]);
            }
        __syncthreads();
    }

    float alpha = alphap[0];
    float scale = powf(sqrtf(outf) / logf(1.0f + outf), alpha);
    #pragma unroll
    for (int j = 0; j < NT; ++j) {
        int col = bn + wc * (BN / WC) + j * 16 + l15;
        float cs = colsq[col], bi = bias[col];
        #pragma unroll
        for (int i = 0; i < MT; ++i) {
            #pragma unroll
            for (int r = 0; r < 4; ++r) {
                int row = bm + wr * (BM / WR) + i * 16 + quad * 4 + r;
                float dot = acc[i][j][r];
                float dist = rowsq[row] + cs - 2.0f * dot + EPSY;
                outp[(size_t)row * N + col] = dot * dot / dist * scale + bi;
            }
        }
    }
}

// ---------------------------------------------------------------------------
// qkv fp32 [B*T, 3C] -> rotary(q,k) -> bf16 Qb (x0.125), Kb, Vb  [b,h,t,d]
__global__ void prep_attn(const float* __restrict__ qkv, u16* __restrict__ Qb,
                          u16* __restrict__ Kb, u16* __restrict__ Vb) {
    int idx = blockIdx.x * 256 + threadIdx.x;   // 2^21 threads
    int j = idx & 31;
    int h = (idx >> 5) & 15;
    int t = (idx >> 9) & 2047;
    int b = idx >> 20;
    size_t row = (size_t)(b * TSEQ + t) * N3C;
    size_t ob = ((size_t)(b * NH + h) * TSEQ + t) * HD;
    float inv = powf(10000.0f, -(float)(2 * j) / 64.0f);
    float ang = (float)t * inv;
    float sn = sinf(ang), cs = cosf(ang);
    float q1 = qkv[row + h * HD + j], q2 = qkv[row + h * HD + j + 32];
    Qb[ob + j]      = f2bf((q1 * cs - q2 * sn) * 0.125f);
    Qb[ob + j + 32] = f2bf((q2 * cs + q1 * sn) * 0.125f);
    float k1 = qkv[row + CDIM + h * HD + j], k2 = qkv[row + CDIM + h * HD + j + 32];
    Kb[ob + j]      = f2bf(k1 * cs - k2 * sn);
    Kb[ob + j + 32] = f2bf(k2 * cs + k1 * sn);
    Vb[ob + j]      = f2bf(qkv[row + 2 * CDIM + h * HD + j]);
    Vb[ob + j + 32] = f2bf(qkv[row + 2 * CDIM + h * HD + j + 32]);
}

// ---------------------------------------------------------------------------
// bf16 MFMA causal flash attention. 64-row Q blocks (1 per wave = 16 rows),
// 32-key tiles. grid (16, B*H); passes (qb, 31-qb) balance causal work.
__global__ __launch_bounds__(256) void attn_mfma(
    const u16* __restrict__ Qb, const u16* __restrict__ Kb,
    const u16* __restrict__ Vb, float* __restrict__ ctx) {
    __shared__ u16 Ksh[32][72];      // [key][d] pad->2-way max
    __shared__ u16 Vsh[64][40];      // [d][key] (transposed at staging)
    __shared__ u16 Psh[4][16][40];   // per-wave P tile [qrow][key]
    int tid = threadIdx.x;
    int lane = tid & 63, wv = tid >> 6;
    int quad = lane >> 4, l15 = lane & 15;
    int bh = blockIdx.y;
    int b = bh >> 4, h = bh & 15;
    const u16* Qh = Qb + (size_t)bh * TSEQ * HD;
    const u16* Kh = Kb + (size_t)bh * TSEQ * HD;
    const u16* Vh = Vb + (size_t)bh * TSEQ * HD;
    const f32x4 zf = {0.f, 0.f, 0.f, 0.f};

    for (int pass = 0; pass < 2; ++pass) {
        int qb = pass ? (31 - blockIdx.x) : blockIdx.x;
        int q0 = qb * 64;
        int qw = q0 + wv * 16;
        bf16x8 aq0 = *(const bf16x8*)(Qh + (size_t)(qw + l15) * HD + quad * 8);
        bf16x8 aq1 = *(const bf16x8*)(Qh + (size_t)(qw + l15) * HD + 32 + quad * 8);

        f32x4 o0 = zf, o1 = zf, o2 = zf, o3 = zf;
        float mrow[4] = {-1e30f, -1e30f, -1e30f, -1e30f};
        float lrow[4] = {0.f, 0.f, 0.f, 0.f};

        int nkt = 2 * (qb + 1);
        for (int kt = 0; kt < nkt; ++kt) {
            int k0 = kt * 32;
            __syncthreads();   // prev tile's LDS reads done before overwrite
            {
                int key = tid >> 3, ch = (tid & 7) * 8;
                bf16x8 kv = *(const bf16x8*)(Kh + (size_t)(k0 + key) * HD + ch);
                *(bf16x8*)&Ksh[key][ch] = kv;
                bf16x8 vv = *(const bf16x8*)(Vh + (size_t)(k0 + key) * HD + ch);
                #pragma unroll
                for (int i = 0; i < 8; ++i) Vsh[ch + i][key] = (u16)vv[i];
            }
            __syncthreads();

            // S = Q K^T (two 16-key column tiles, d split 0..31 / 32..63)
            f32x4 s0 = MFMA16(aq0, *(const bf16x8*)&Ksh[l15][quad * 8], zf);
            s0 = MFMA16(aq1, *(const bf16x8*)&Ksh[l15][32 + quad * 8], s0);
            f32x4 s1 = MFMA16(aq0, *(const bf16x8*)&Ksh[16 + l15][quad * 8], zf);
            s1 = MFMA16(aq1, *(const bf16x8*)&Ksh[16 + l15][32 + quad * 8], s1);

            if (k0 + 31 > qw) {   // causal mask (diagonal tiles only)
                int tq = qw + quad * 4;
                #pragma unroll
                for (int r = 0; r < 4; ++r) {
                    if (k0 + l15 > tq + r)      s0[r] = -1e30f;
                    if (k0 + 16 + l15 > tq + r) s1[r] = -1e30f;
                }
            }
            // online softmax (row = quad*4+r spans the 16 lanes of this quad)
            #pragma unroll
            for (int r = 0; r < 4; ++r) {
                float mx = fmaxf(s0[r], s1[r]);
                #pragma unroll
                for (int off = 1; off < 16; off <<= 1) mx = fmaxf(mx, __shfl_xor(mx, off, 64));
                float mn = fmaxf(mrow[r], mx);
                float al = __expf(mrow[r] - mn);
                float p0 = __expf(s0[r] - mn);
                float p1 = __expf(s1[r] - mn);
                float ps = p0 + p1;
                #pragma unroll
                for (int off = 1; off < 16; off <<= 1) ps += __shfl_xor(ps, off, 64);
                lrow[r] = lrow[r] * al + ps;
                mrow[r] = mn;
                o0[r] *= al; o1[r] *= al; o2[r] *= al; o3[r] *= al;
                Psh[wv][quad * 4 + r][l15] = f2bf(p0);
                Psh[wv][quad * 4 + r][16 + l15] = f2bf(p1);
            }
            // P (C-layout) -> A-layout via per-wave LDS; intra-wave dep only
            bf16x8 ap = *(const bf16x8*)&Psh[wv][l15][quad * 8];
            o0 = MFMA16(ap, *(const bf16x8*)&Vsh[l15][quad * 8], o0);
            o1 = MFMA16(ap, *(const bf16x8*)&Vsh[16 + l15][quad * 8], o1);
            o2 = MFMA16(ap, *(const bf16x8*)&Vsh[32 + l15][quad * 8], o2);
            o3 = MFMA16(ap, *(const bf16x8*)&Vsh[48 + l15][quad * 8], o3);
        }

        #pragma unroll
        for (int r = 0; r < 4; ++r) {
            int trow = qw + quad * 4 + r;
            float inv = 1.0f / lrow[r];
            float* dst = ctx + ((size_t)b * TSEQ + trow) * CDIM + h * HD;
            dst[l15]      = o0[r] * inv;
            dst[16 + l15] = o1[r] * inv;
            dst[32 + l15] = o2[r] * inv;
            dst[48 + l15] = o3[r] * inv;
        }
    }
}

// ---------------------------------------------------------------------------
extern "C" void kernel_launch(void* const* d_in, const int* in_sizes, int n_in,
                              void* d_out, int out_size, void* d_ws, size_t ws_size,
                              hipStream_t stream) {
    const float* x      = (const float*)d_in[0];
    const float* w_attn = (const float*)d_in[2];
    const float* b_attn = (const float*)d_in[3];
    const float* a_attn = (const float*)d_in[4];
    const float* w_proj = (const float*)d_in[5];
    const float* b_proj = (const float*)d_in[6];
    const float* a_proj = (const float*)d_in[7];
    float* outp = (float*)d_out;

    char* ws = (char*)d_ws;
    float* ksq = (float*)(ws);            // 16 KB
    float* xsq = (float*)(ws + 16384);
    float* osq = (float*)(ws + 32768);
    // Region A (phased reuse):
    char* base0 = ws + 65536;
    u16* Wthi = (u16*)(base0);                       // 3072x1024 bf16
    u16* Wtlo = (u16*)(base0 + 6291456);
    u16* Ahi  = (u16*)(base0 + 12582912);            // 4096x1024 bf16
    u16* Alo  = (u16*)(base0 + 20971520);
    u16* Qb   = (u16*)(base0);                       // reuse: post-GEMM1
    u16* Kb   = (u16*)(base0 + 8388608);
    u16* Vb   = (u16*)(base0 + 16777216);
    u16* Chi  = (u16*)(base0);                       // reuse: post-attention
    u16* Clo  = (u16*)(base0 + 8388608);
    char* base1 = ws + 65536 + 29360128;
    u16* Wphi = (u16*)(base1);                       // 1024x1024 bf16
    u16* Wplo = (u16*)(base1 + 2097152);
    char* base2 = base1 + 4194304;
    float* qkv = (float*)(base2);                    // 4096x3072 fp32
    float* ctx = (float*)(base2);                    // aliases qkv (dead after prep)

    colsq_kernel<<<64, 256, 0, stream>>>(w_attn, w_proj, ksq);
    convert_rows<<<BATCH * TSEQ, 256, 0, stream>>>(x, Ahi, Alo, xsq);
    convert_wT<<<dim3(N3C / 64, CDIM / 64), 256, 0, stream>>>(w_attn, Wthi, Wtlo, CDIM, N3C);
    convert_wT<<<dim3(CDIM / 64, CDIM / 64), 256, 0, stream>>>(w_proj, Wphi, Wplo, CDIM, CDIM);
    gemm_yat_mfma<128, 2, 2><<<dim3(N3C / 128, (BATCH * TSEQ) / 128), 256, 0, stream>>>(
        Ahi, Alo, Wthi, Wtlo, b_attn, xsq, ksq, a_attn, qkv,
        BATCH * TSEQ, N3C, CDIM, (float)N3C);
    prep_attn<<<(BATCH * TSEQ * NH * 32) / 256, 256, 0, stream>>>(qkv, Qb, Kb, Vb);
    attn_mfma<<<dim3(16, BATCH * NH), 256, 0, stream>>>(Qb, Kb, Vb, ctx);
    convert_rows<<<BATCH * TSEQ, 256, 0, stream>>>(ctx, Chi, Clo, osq);
    gemm_yat_mfma<64, 4, 1><<<dim3(CDIM / 64, (BATCH * TSEQ) / 128), 256, 0, stream>>>(
        Chi, Clo, Wphi, Wplo, b_proj, osq, ksq + N3C, a_proj, outp,
        BATCH * TSEQ, CDIM, CDIM, (float)CDIM);
}

// Round 4
// 343.891 us; speedup vs baseline: 3.0256x; 1.2441x over previous
//
#include <hip/hip_runtime.h>
#include <math.h>

#define TSEQ  2048
#define BATCH 2
#define NH    16
#define HD    64
#define CDIM  1024
#define N3C   3072
#define EPSY  1e-6f

typedef unsigned short u16;
typedef unsigned int u32;
typedef __attribute__((ext_vector_type(8))) short bf16x8;
typedef __attribute__((ext_vector_type(4))) float f32x4;

#define MFMA16(a, b, c) __builtin_amdgcn_mfma_f32_16x16x32_bf16(a, b, c, 0, 0, 0)

__device__ __forceinline__ u16 f2bf(float f) {
    unsigned u = __float_as_uint(f);
    return (u16)((u + 0x7fffu + ((u >> 16) & 1u)) >> 16);
}
__device__ __forceinline__ float bf2f(u16 h) {
    return __uint_as_float(((unsigned)h) << 16);
}
__device__ __forceinline__ void gload16(const void* g, void* l) {
    __builtin_amdgcn_global_load_lds(
        (const __attribute__((address_space(1))) unsigned int*)g,
        (__attribute__((address_space(3))) unsigned int*)l, 16, 0, 0);
}

// ---------------------------------------------------------------------------
__global__ void colsq_kernel(const float* __restrict__ wa,
                             const float* __restrict__ wp,
                             float* __restrict__ ks) {
    int bid = blockIdx.x, tid = threadIdx.x;
    int c = tid & 63, kq = tid >> 6;
    const float* W; int N, col, outoff;
    if (bid < 48) { W = wa; N = N3C;  col = bid * 64 + c;        outoff = 0;   }
    else          { W = wp; N = CDIM; col = (bid - 48) * 64 + c; outoff = N3C; }
    float s = 0.f;
    int i0 = kq * 256;
    #pragma unroll 4
    for (int i = i0; i < i0 + 256; ++i) {
        float v = W[(size_t)i * N + col];
        s = fmaf(v, v, s);
    }
    __shared__ float red[256];
    red[tid] = s;
    __syncthreads();
    if (kq == 0) ks[outoff + col] = red[c] + red[64 + c] + red[128 + c] + red[192 + c];
}

// ---------------------------------------------------------------------------
__global__ void convert_rows(const float* __restrict__ X, u16* __restrict__ Xhi,
                             u16* __restrict__ Xlo, float* __restrict__ rsq) {
    int row = blockIdx.x, tid = threadIdx.x;
    int lane = tid & 63, wv = tid >> 6;
    size_t base = (size_t)row * CDIM + tid * 4;
    float4 v = *(const float4*)(X + base);
    ushort4 hi, lo;
    hi.x = f2bf(v.x); lo.x = f2bf(v.x - bf2f(hi.x));
    hi.y = f2bf(v.y); lo.y = f2bf(v.y - bf2f(hi.y));
    hi.z = f2bf(v.z); lo.z = f2bf(v.z - bf2f(hi.z));
    hi.w = f2bf(v.w); lo.w = f2bf(v.w - bf2f(hi.w));
    *(ushort4*)(Xhi + base) = hi;
    *(ushort4*)(Xlo + base) = lo;
    float s = v.x * v.x + v.y * v.y + v.z * v.z + v.w * v.w;
    #pragma unroll
    for (int off = 32; off; off >>= 1) s += __shfl_down(s, off, 64);
    __shared__ float red[4];
    if (lane == 0) red[wv] = s;
    __syncthreads();
    if (tid == 0) rsq[row] = red[0] + red[1] + red[2] + red[3];
}

// ---------------------------------------------------------------------------
__global__ void convert_wT(const float* __restrict__ W, u16* __restrict__ Whi,
                           u16* __restrict__ Wlo, int K, int N) {
    __shared__ float tile[64][68];
    int k0 = blockIdx.y * 64, n0 = blockIdx.x * 64;
    int tid = threadIdx.x;
    int r = tid >> 4, c4 = (tid & 15) * 4;
    #pragma unroll
    for (int i = 0; i < 4; ++i) {
        int k = k0 + r + i * 16;
        float4 v = *(const float4*)(W + (size_t)k * N + n0 + c4);
        *(float4*)&tile[r + i * 16][c4] = v;
    }
    __syncthreads();
    int n = tid >> 4, k4 = (tid & 15) * 4;
    #pragma unroll
    for (int i = 0; i < 4; ++i) {
        int nn = n + i * 16;
        float a = tile[k4 + 0][nn], b = tile[k4 + 1][nn];
        float c = tile[k4 + 2][nn], d = tile[k4 + 3][nn];
        ushort4 hi, lo;
        hi.x = f2bf(a); lo.x = f2bf(a - bf2f(hi.x));
        hi.y = f2bf(b); lo.y = f2bf(b - bf2f(hi.y));
        hi.z = f2bf(c); lo.z = f2bf(c - bf2f(hi.z));
        hi.w = f2bf(d); lo.w = f2bf(d - bf2f(hi.w));
        size_t o = (size_t)(n0 + nn) * K + k0 + k4;
        *(ushort4*)(Whi + o) = hi;
        *(ushort4*)(Wlo + o) = lo;
    }
}

// ---------------------------------------------------------------------------
// GEMM1: split-bf16 MFMA, yat epilogue fused with rotary + bf16 pack.
// Writes Qb (x0.125, rotary), Kb (rotary) in [b,h,t,d]; Vt transposed [b,h,d,t].
__global__ __launch_bounds__(256) void gemm1_fused(
    const u16* __restrict__ Ah, const u16* __restrict__ Al,
    const u16* __restrict__ Bh, const u16* __restrict__ Bl,
    const float* __restrict__ bias, const float* __restrict__ rowsq,
    const float* __restrict__ colsq, const float* __restrict__ alphap,
    u16* __restrict__ Qb, u16* __restrict__ Kb, u16* __restrict__ Vt) {
    constexpr int BK = 32;
    const int K = CDIM;
    __shared__ u16 Ash[128 * BK], Asl[128 * BK], Bsh[128 * BK], Bsl[128 * BK];
    int tid = threadIdx.x;
    int lane = tid & 63, wv = tid >> 6;
    int quad = lane >> 4, l15 = lane & 15;
    int wr = wv >> 1, wc = wv & 1;
    int bm = blockIdx.y * 128, bn = blockIdx.x * 128;
    int rsub = lane >> 2, csub = (lane & 3) * 8;

    f32x4 acc[4][4];
    #pragma unroll
    for (int i = 0; i < 4; ++i)
        #pragma unroll
        for (int j = 0; j < 4; ++j) acc[i][j] = (f32x4){0.f, 0.f, 0.f, 0.f};

    for (int kt = 0; kt < K; kt += BK) {
        #pragma unroll
        for (int i = 0; i < 2; ++i) {
            int r = i * 64 + wv * 16 + rsub;
            size_t go = (size_t)(bm + r) * K + kt + csub;
            gload16(Ah + go, &Ash[r * BK + csub]);
            gload16(Al + go, &Asl[r * BK + csub]);
            size_t gb = (size_t)(bn + r) * K + kt + csub;
            gload16(Bh + gb, &Bsh[r * BK + csub]);
            gload16(Bl + gb, &Bsl[r * BK + csub]);
        }
        __syncthreads();
        bf16x8 fah[4], fal[4], fbh[4], fbl[4];
        #pragma unroll
        for (int i = 0; i < 4; ++i) {
            int r = wr * 64 + i * 16 + l15;
            fah[i] = *(const bf16x8*)&Ash[r * BK + quad * 8];
            fal[i] = *(const bf16x8*)&Asl[r * BK + quad * 8];
        }
        #pragma unroll
        for (int j = 0; j < 4; ++j) {
            int r = wc * 64 + j * 16 + l15;
            fbh[j] = *(const bf16x8*)&Bsh[r * BK + quad * 8];
            fbl[j] = *(const bf16x8*)&Bsl[r * BK + quad * 8];
        }
        #pragma unroll
        for (int i = 0; i < 4; ++i)
            #pragma unroll
            for (int j = 0; j < 4; ++j) {
                acc[i][j] = MFMA16(fah[i], fbh[j], acc[i][j]);
                acc[i][j] = MFMA16(fal[i], fbh[j], acc[i][j]);
                acc[i][j] = MFMA16(fah[i], fbl[j], acc[i][j]);
            }
        __syncthreads();
    }

    float alpha = alphap[0];
    float scale = powf(sqrtf((float)N3C) / logf(1.0f + (float)N3C), alpha);
    int segc0 = bn + wc * 64;          // wave-uniform
    int seg = segc0 >> 10;             // 0=Q 1=K 2=V
    int h = (segc0 >> 6) & 15;
    int bglob = bm >> 11;
    int bh = bglob * NH + h;

    if (seg < 2) {
        u16* dst = (seg == 0) ? Qb : Kb;
        float qs = (seg == 0) ? 0.125f : 1.0f;
        // inv_freq for i=l15 and i=l15+16   (log2(10000)/32)
        float inv0 = exp2f(-(float)l15 * 0.4152410118609203f);
        float inv1 = exp2f(-(float)(l15 + 16) * 0.4152410118609203f);
        #pragma unroll
        for (int i = 0; i < 4; ++i) {
            int tb = bm + wr * 64 + i * 16 + quad * 4;
            #pragma unroll
            for (int r = 0; r < 4; ++r) {
                int row = tb + r;
                int t = row & (TSEQ - 1);
                float rs = rowsq[row];
                float y[4];
                #pragma unroll
                for (int j = 0; j < 4; ++j) {
                    int col = segc0 + j * 16 + l15;
                    float dot = acc[i][j][r];
                    float dist = rs + colsq[col] - 2.0f * dot + EPSY;
                    y[j] = dot * dot / dist * scale + bias[col];
                }
                float s0, c0, s1, c1;
                sincosf((float)t * inv0, &s0, &c0);
                sincosf((float)t * inv1, &s1, &c1);
                size_t ob = ((size_t)bh * TSEQ + t) * HD;
                dst[ob + l15]      = f2bf((y[0] * c0 - y[2] * s0) * qs);
                dst[ob + 16 + l15] = f2bf((y[1] * c1 - y[3] * s1) * qs);
                dst[ob + 32 + l15] = f2bf((y[2] * c0 + y[0] * s0) * qs);
                dst[ob + 48 + l15] = f2bf((y[3] * c1 + y[1] * s1) * qs);
            }
        }
    } else {
        #pragma unroll
        for (int i = 0; i < 4; ++i) {
            int tb = bm + wr * 64 + i * 16 + quad * 4;
            int t0 = tb & (TSEQ - 1);
            #pragma unroll
            for (int j = 0; j < 4; ++j) {
                int col = segc0 + j * 16 + l15;
                int d = j * 16 + l15;
                float cs = colsq[col], bi = bias[col];
                ushort4 pk;
                u16* pp = (u16*)&pk;
                #pragma unroll
                for (int r = 0; r < 4; ++r) {
                    float dot = acc[i][j][r];
                    float dist = rowsq[tb + r] + cs - 2.0f * dot + EPSY;
                    pp[r] = f2bf(dot * dot / dist * scale + bi);
                }
                *(ushort4*)(Vt + ((size_t)bh * HD + d) * TSEQ + t0) = pk;
            }
        }
    }
}

// ---------------------------------------------------------------------------
// GEMM2: split-bf16 MFMA + yat epilogue, fp32 out. (128x64 tile, WR=4)
__global__ __launch_bounds__(256) void gemm_yat_mfma(
    const u16* __restrict__ Ah, const u16* __restrict__ Al,
    const u16* __restrict__ Bh, const u16* __restrict__ Bl,
    const float* __restrict__ bias, const float* __restrict__ rowsq,
    const float* __restrict__ colsq, const float* __restrict__ alphap,
    float* __restrict__ outp, int M, int N, int K, float outf) {
    constexpr int BM = 128, BN = 64, BK = 32;
    __shared__ u16 Ash[BM * BK], Asl[BM * BK], Bsh[BN * BK], Bsl[BN * BK];
    int tid = threadIdx.x;
    int lane = tid & 63, wv = tid >> 6;
    int quad = lane >> 4, l15 = lane & 15;
    int bm = blockIdx.y * BM, bn = blockIdx.x * BN;
    int rsub = lane >> 2, csub = (lane & 3) * 8;

    f32x4 acc[2][4];
    #pragma unroll
    for (int i = 0; i < 2; ++i)
        #pragma unroll
        for (int j = 0; j < 4; ++j) acc[i][j] = (f32x4){0.f, 0.f, 0.f, 0.f};

    for (int kt = 0; kt < K; kt += BK) {
        #pragma unroll
        for (int i = 0; i < 2; ++i) {
            int r = i * 64 + wv * 16 + rsub;
            size_t go = (size_t)(bm + r) * K + kt + csub;
            gload16(Ah + go, &Ash[r * BK + csub]);
            gload16(Al + go, &Asl[r * BK + csub]);
        }
        {
            int r = wv * 16 + rsub;
            size_t go = (size_t)(bn + r) * K + kt + csub;
            gload16(Bh + go, &Bsh[r * BK + csub]);
            gload16(Bl + go, &Bsl[r * BK + csub]);
        }
        __syncthreads();
        bf16x8 fah[2], fal[2], fbh[4], fbl[4];
        #pragma unroll
        for (int i = 0; i < 2; ++i) {
            int r = wv * 32 + i * 16 + l15;
            fah[i] = *(const bf16x8*)&Ash[r * BK + quad * 8];
            fal[i] = *(const bf16x8*)&Asl[r * BK + quad * 8];
        }
        #pragma unroll
        for (int j = 0; j < 4; ++j) {
            int r = j * 16 + l15;
            fbh[j] = *(const bf16x8*)&Bsh[r * BK + quad * 8];
            fbl[j] = *(const bf16x8*)&Bsl[r * BK + quad * 8];
        }
        #pragma unroll
        for (int i = 0; i < 2; ++i)
            #pragma unroll
            for (int j = 0; j < 4; ++j) {
                acc[i][j] = MFMA16(fah[i], fbh[j], acc[i][j]);
                acc[i][j] = MFMA16(fal[i], fbh[j], acc[i][j]);
                acc[i][j] = MFMA16(fah[i], fbl[j], acc[i][j]);
            }
        __syncthreads();
    }

    float alpha = alphap[0];
    float scale = powf(sqrtf(outf) / logf(1.0f + outf), alpha);
    #pragma unroll
    for (int j = 0; j < 4; ++j) {
        int col = bn + j * 16 + l15;
        float cs = colsq[col], bi = bias[col];
        #pragma unroll
        for (int i = 0; i < 2; ++i) {
            #pragma unroll
            for (int r = 0; r < 4; ++r) {
                int row = bm + wv * 32 + i * 16 + quad * 4 + r;
                float dot = acc[i][j][r];
                float dist = rowsq[row] + cs - 2.0f * dot + EPSY;
                outp[(size_t)row * N + col] = dot * dot / dist * scale + bi;
            }
        }
    }
}

// ---------------------------------------------------------------------------
// S^T-formulation bf16 MFMA causal flash attention.
// S^T = K Q^T (A=K natural, B=Q natural); O^T = V^T P^T (A=V^T, B=P^T via shfl).
// 64-key tiles, swizzled gload16 staging, grid (16, B*H), paired (qb, 31-qb).
__global__ __launch_bounds__(256) void attn_mfma(
    const u16* __restrict__ Qb, const u16* __restrict__ Kb,
    const u16* __restrict__ Vt, float* __restrict__ ctx) {
    __shared__ u16 Ksh[64 * 64];   // [key][d-chunks, rotated by key]
    __shared__ u16 Vsh[64 * 64];   // [d][key-chunks, rotated by d]
    int tid = threadIdx.x;
    int lane = tid & 63, wv = tid >> 6;
    int quad = lane >> 4, l15 = lane & 15;
    int bh = blockIdx.y;
    int b = bh >> 4, h = bh & 15;
    const u16* Qh = Qb + (size_t)bh * TSEQ * HD;
    const u16* Kh = Kb + (size_t)bh * TSEQ * HD;
    const u16* Vh = Vt + (size_t)bh * HD * TSEQ;
    const f32x4 zf = {0.f, 0.f, 0.f, 0.f};

    for (int pass = 0; pass < 2; ++pass) {
        int qb = pass ? (31 - blockIdx.x) : blockIdx.x;
        int qw = qb * 64 + wv * 16;
        bf16x8 bq0 = *(const bf16x8*)(Qh + (size_t)(qw + l15) * HD + quad * 8);
        bf16x8 bq1 = *(const bf16x8*)(Qh + (size_t)(qw + l15) * HD + 32 + quad * 8);

        f32x4 o[4] = {zf, zf, zf, zf};
        float m = -1e30f, l = 0.f;

        for (int kt = 0; kt <= qb; ++kt) {
            int k0 = kt * 64;
            __syncthreads();
            #pragma unroll
            for (int p = 0; p < 2; ++p) {
                int lin = p * 256 + tid;
                int rowi = lin >> 3, ch = lin & 7;
                int gk = (ch + rowi) & 7;
                gload16(Kh + (size_t)(k0 + rowi) * HD + gk * 8, &Ksh[lin * 8]);
                gload16(Vh + (size_t)rowi * TSEQ + k0 + gk * 8, &Vsh[lin * 8]);
            }
            __syncthreads();

            // S^T: 4 key-tiles x 2 d-steps
            f32x4 st[4];
            #pragma unroll
            for (int mt = 0; mt < 4; ++mt) {
                int key = mt * 16 + l15;
                bf16x8 a0 = *(const bf16x8*)&Ksh[key * 64 + ((quad - key) & 7) * 8];
                bf16x8 a1 = *(const bf16x8*)&Ksh[key * 64 + ((4 + quad - key) & 7) * 8];
                st[mt] = MFMA16(a0, bq0, zf);
                st[mt] = MFMA16(a1, bq1, st[mt]);
            }
            if (kt == qb) {   // causal mask on diagonal tile
                int q = qw + l15;
                #pragma unroll
                for (int mt = 0; mt < 4; ++mt)
                    #pragma unroll
                    for (int r = 0; r < 4; ++r)
                        if (k0 + mt * 16 + quad * 4 + r > q) st[mt][r] = -1e30f;
            }
            // softmax over keys (regs + cross-quad reduce; lane l15 = query)
            float mx = -1e30f;
            #pragma unroll
            for (int mt = 0; mt < 4; ++mt)
                #pragma unroll
                for (int r = 0; r < 4; ++r) mx = fmaxf(mx, st[mt][r]);
            mx = fmaxf(mx, __shfl_xor(mx, 16, 64));
            mx = fmaxf(mx, __shfl_xor(mx, 32, 64));
            float mn = fmaxf(m, mx);
            float al = __expf(m - mn);
            m = mn;
            float ps = 0.f;
            u32 pp[4][2];
            #pragma unroll
            for (int mt = 0; mt < 4; ++mt) {
                float p0 = __expf(st[mt][0] - mn);
                float p1 = __expf(st[mt][1] - mn);
                float p2 = __expf(st[mt][2] - mn);
                float p3 = __expf(st[mt][3] - mn);
                ps += (p0 + p1) + (p2 + p3);
                pp[mt][0] = (u32)f2bf(p0) | ((u32)f2bf(p1) << 16);
                pp[mt][1] = (u32)f2bf(p2) | ((u32)f2bf(p3) << 16);
            }
            ps += __shfl_xor(ps, 16, 64);
            ps += __shfl_xor(ps, 32, 64);
            l = l * al + ps;
            #pragma unroll
            for (int dt = 0; dt < 4; ++dt) {
                o[dt][0] *= al; o[dt][1] *= al; o[dt][2] *= al; o[dt][3] *= al;
            }
            // PV: 2 k-steps of 32 keys. B-fragment needs, at dest lane
            // (quad,l15), keys s*32+quad*8+2w+{0,1} of query l15 — i.e. source
            // lane quad' = (quad&1)*2+(w>>1), pack pp[2s+(quad>>1)][w&1].
            // Shuffle BOTH mt-candidates, select on the DESTINATION side
            // (R3 bug: selecting before shuffle used the source's quad).
            #pragma unroll
            for (int s = 0; s < 2; ++s) {
                u32 bw[4];
                #pragma unroll
                for (int w = 0; w < 4; ++w) {
                    int srcl = (((quad & 1) * 2 + (w >> 1)) << 4) + l15;
                    u32 vlo = (u32)__shfl((int)pp[2 * s][w & 1], srcl, 64);
                    u32 vhi = (u32)__shfl((int)pp[2 * s + 1][w & 1], srcl, 64);
                    bw[w] = (quad & 2) ? vhi : vlo;
                }
                bf16x8 bfr;
                *(u32*)&((short*)&bfr)[0] = bw[0];
                *(u32*)&((short*)&bfr)[2] = bw[1];
                *(u32*)&((short*)&bfr)[4] = bw[2];
                *(u32*)&((short*)&bfr)[6] = bw[3];
                #pragma unroll
                for (int dt = 0; dt < 4; ++dt) {
                    int d = dt * 16 + l15;
                    bf16x8 av = *(const bf16x8*)&Vsh[d * 64 + ((s * 4 + quad - d) & 7) * 8];
                    o[dt] = MFMA16(av, bfr, o[dt]);
                }
            }
        }

        float inv = 1.0f / l;
        #pragma unroll
        for (int dt = 0; dt < 4; ++dt) {
            float4 r;
            r.x = o[dt][0] * inv; r.y = o[dt][1] * inv;
            r.z = o[dt][2] * inv; r.w = o[dt][3] * inv;
            *(float4*)(ctx + ((size_t)b * TSEQ + qw + l15) * CDIM
                       + h * HD + dt * 16 + quad * 4) = r;
        }
    }
}

// ---------------------------------------------------------------------------
extern "C" void kernel_launch(void* const* d_in, const int* in_sizes, int n_in,
                              void* d_out, int out_size, void* d_ws, size_t ws_size,
                              hipStream_t stream) {
    const float* x      = (const float*)d_in[0];
    const float* w_attn = (const float*)d_in[2];
    const float* b_attn = (const float*)d_in[3];
    const float* a_attn = (const float*)d_in[4];
    const float* w_proj = (const float*)d_in[5];
    const float* b_proj = (const float*)d_in[6];
    const float* a_proj = (const float*)d_in[7];
    float* outp = (float*)d_out;

    char* ws = (char*)d_ws;
    float* ksq = (float*)(ws);
    float* xsq = (float*)(ws + 16384);
    float* osq = (float*)(ws + 32768);
    char* pA  = ws + 65536;                    // 16.78 MB: Ahi/Alo -> ctx
    u16* Ahi = (u16*)pA;
    u16* Alo = (u16*)(pA + 8388608);
    float* ctx = (float*)pA;                   // alias (A dead after GEMM1)
    char* pWt = pA + 16777216;                 // 12.58 MB
    u16* Wthi = (u16*)pWt;
    u16* Wtlo = (u16*)(pWt + 6291456);
    char* pWp = pWt + 12582912;                // 4.19 MB
    u16* Wphi = (u16*)pWp;
    u16* Wplo = (u16*)(pWp + 2097152);
    char* pQ = pWp + 4194304;                  // 25.17 MB: Qb,Kb,Vt
    u16* Qb = (u16*)pQ;
    u16* Kb = (u16*)(pQ + 8388608);
    u16* Vt = (u16*)(pQ + 16777216);
    u16* Chi = (u16*)pQ;                       // alias (Q/K dead after attn)
    u16* Clo = (u16*)(pQ + 8388608);

    colsq_kernel<<<64, 256, 0, stream>>>(w_attn, w_proj, ksq);
    convert_rows<<<BATCH * TSEQ, 256, 0, stream>>>(x, Ahi, Alo, xsq);
    convert_wT<<<dim3(N3C / 64, CDIM / 64), 256, 0, stream>>>(w_attn, Wthi, Wtlo, CDIM, N3C);
    convert_wT<<<dim3(CDIM / 64, CDIM / 64), 256, 0, stream>>>(w_proj, Wphi, Wplo, CDIM, CDIM);
    gemm1_fused<<<dim3(N3C / 128, (BATCH * TSEQ) / 128), 256, 0, stream>>>(
        Ahi, Alo, Wthi, Wtlo, b_attn, xsq, ksq, a_attn, Qb, Kb, Vt);
    attn_mfma<<<dim3(16, BATCH * NH), 256, 0, stream>>>(Qb, Kb, Vt, ctx);
    convert_rows<<<BATCH * TSEQ, 256, 0, stream>>>(ctx, Chi, Clo, osq);
    gemm_yat_mfma<<<dim3(CDIM / 64, (BATCH * TSEQ) / 128), 256, 0, stream>>>(
        Chi, Clo, Wphi, Wplo, b_proj, osq, ksq + N3C, a_proj, outp,
        BATCH * TSEQ, CDIM, CDIM, (float)CDIM);
}